// Round 2
// baseline (1026.219 us; speedup 1.0000x reference)
//
#include <hip/hip_runtime.h>

#define HDIM 128
#define KSAMP 64
#define RPB 2            // rays per block
#define SPB 128          // samples per block (RPB * KSAMP)
#define T1 256           // threads in render kernel

__device__ __forceinline__ float sigmoidf_(float x){ return 1.f/(1.f+expf(-x)); }

// ---------------------------------------------------------------------------
// render_k: one block = 2 rays (128 samples). Static 64 KiB LDS, K-split GEMM.
//   phase 0: stage W2 rows 0..63 + compute h1 features 0..63 -> GEMM partial
//   phase 1: same for rows/features 64..127 (same acc registers)
//   epilogue: h2=relu(acc) -> LDS (full 64KB as [128][128]) -> layer3 ->
//             sigmoid/sigma -> wave prefix-product compositing -> per-ray
//             softmax sufficient statistics to ws.
// ---------------------------------------------------------------------------
__global__ __launch_bounds__(T1) void render_k(
    const float* __restrict__ rays, const float* __restrict__ z_samp,
    const unsigned char* __restrict__ invalid,
    const float* __restrict__ W1, const float* __restrict__ b1,
    const float* __restrict__ W2, const float* __restrict__ b2,
    const float* __restrict__ W3, const float* __restrict__ b3,
    float* __restrict__ out_rgb, float* __restrict__ out_depth,
    float* __restrict__ out_w, float* __restrict__ stat, int nr)
{
    __shared__ float lds[16384];          // exactly 64 KiB static
    float* W2h = lds;                     // [64][128] rows k of W2 (per phase)
    float* h1h = lds + 8192;              // [64][128] feature-major h1 (per phase)

    const int tid  = threadIdx.x;
    const int ray0 = blockIdx.x * RPB;
    const int s    = tid & 127;           // sample within block
    const int part = tid >> 7;            // 0/1 (feature half within phase)
    const int ray  = ray0 + (s >> 6);

    // per-thread ray data (wave-uniform -> scalar loads)
    const float* rp = rays + (size_t)ray * 8;
    const float o0 = rp[0], o1 = rp[1], o2 = rp[2];
    const float d0 = rp[3], d1 = rp[4], d2 = rp[5];
    const float z  = z_samp[(size_t)ray0 * KSAMP + s];

    // 8 samples x 8 features register tile
    const int sBase = (tid & 15) * 8;
    const int fBase = (tid >> 4) * 8;
    float acc[8][8];
    {
        float4 bb0 = *(const float4*)&b2[fBase];
        float4 bb1 = *(const float4*)&b2[fBase + 4];
        float bi[8] = {bb0.x,bb0.y,bb0.z,bb0.w,bb1.x,bb1.y,bb1.z,bb1.w};
        #pragma unroll
        for (int i = 0; i < 8; ++i)
            #pragma unroll
            for (int j = 0; j < 8; ++j) acc[i][j] = bi[j];
    }

    #pragma unroll
    for (int phase = 0; phase < 2; ++phase){
        // ---- stage W2 rows [phase*64, phase*64+64) ----
        {
            const float4* src = (const float4*)(W2 + (size_t)phase * 64 * HDIM);
            float4* dst = (float4*)W2h;
            #pragma unroll
            for (int i = 0; i < 8; ++i) dst[tid + i*T1] = src[tid + i*T1];
        }
        // ---- layer 1 for features f = phase*64 + part*32 + j ----
        {
            #pragma unroll 4
            for (int j = 0; j < 32; ++j){
                int fl = part*32 + j;              // local feature 0..63
                int f  = phase*64 + fl;            // global feature
                float w0 = W1[f], w1 = W1[HDIM+f], w2 = W1[2*HDIM+f];
                float ow = fmaf(o0,w0, fmaf(o1,w1, fmaf(o2,w2, b1[f])));
                float dw = fmaf(d0,w0, fmaf(d1,w1, d2*w2));
                h1h[fl*SPB + s] = fmaxf(fmaf(z, dw, ow), 0.f);
            }
        }
        __syncthreads();
        // ---- GEMM partial over k in [0,64) of this phase ----
        #pragma unroll 2
        for (int k = 0; k < 64; ++k){
            float4 a0 = *(const float4*)&h1h[k*SPB + sBase];
            float4 a1 = *(const float4*)&h1h[k*SPB + sBase + 4];
            float4 b0 = *(const float4*)&W2h[k*HDIM + fBase];
            float4 c1 = *(const float4*)&W2h[k*HDIM + fBase + 4];
            float av[8] = {a0.x,a0.y,a0.z,a0.w,a1.x,a1.y,a1.z,a1.w};
            float bv[8] = {b0.x,b0.y,b0.z,b0.w,c1.x,c1.y,c1.z,c1.w};
            #pragma unroll
            for (int i = 0; i < 8; ++i)
                #pragma unroll
                for (int j = 0; j < 8; ++j)
                    acc[i][j] = fmaf(av[i], bv[j], acc[i][j]);
        }
        __syncthreads();   // all reads done before next phase overwrites LDS
    }

    // ---- h2 = relu(acc) -> whole LDS as h2t[128 features][128 samples] ----
    #pragma unroll
    for (int j = 0; j < 8; ++j){
        float4 v0 = make_float4(fmaxf(acc[0][j],0.f), fmaxf(acc[1][j],0.f),
                                fmaxf(acc[2][j],0.f), fmaxf(acc[3][j],0.f));
        float4 v1 = make_float4(fmaxf(acc[4][j],0.f), fmaxf(acc[5][j],0.f),
                                fmaxf(acc[6][j],0.f), fmaxf(acc[7][j],0.f));
        *(float4*)&lds[(fBase+j)*SPB + sBase]     = v0;
        *(float4*)&lds[(fBase+j)*SPB + sBase + 4] = v1;
    }
    __syncthreads();

    // ---- layer 3 + compositing: threads 0..127, wave w handles ray ray0+w --
    if (tid < SPB){
        const int lane = tid & 63;
        float4 b3v = *(const float4*)&b3[0];
        float p0 = b3v.x, p1 = b3v.y, p2 = b3v.z, p3 = b3v.w;
        #pragma unroll 8
        for (int k = 0; k < HDIM; ++k){
            float h = lds[k*SPB + tid];            // 64 consecutive lanes: no conflict
            float4 w3 = *(const float4*)&W3[k*4];  // wave-uniform
            p0 = fmaf(h,w3.x,p0); p1 = fmaf(h,w3.y,p1);
            p2 = fmaf(h,w3.z,p2); p3 = fmaf(h,w3.w,p3);
        }
        const size_t gidx = (size_t)ray0 * KSAMP + tid;
        const float sigma = p3;
        const float sv = invalid[gidx] ? 0.f : sigma;   // masked sigma for loss

        // deltas + alpha
        float zn = __shfl_down(z, 1);
        float delta = (lane == 63) ? 1e10f : (zn - z);
        float alpha = 1.f - expf(-fabsf(delta) * fmaxf(sigma, 0.f));
        float shifted = 1.f - alpha + 1e-10f;
        // exclusive prefix product across the 64-lane wave
        float pr = shifted;
        #pragma unroll
        for (int o = 1; o < 64; o <<= 1){
            float v = __shfl_up(pr, o);
            if (lane >= o) pr *= v;
        }
        float T = __shfl_up(pr, 1);
        if (lane == 0) T = 1.f;
        const float w = alpha * T;
        out_w[gidx] = w;

        float rr = sigmoidf_(p0), gg = sigmoidf_(p1), bb = sigmoidf_(p2);
        float vr = w*rr, vg = w*gg, vb = w*bb, vd = w*z;
        #pragma unroll
        for (int o = 32; o > 0; o >>= 1){
            vr += __shfl_xor(vr, o); vg += __shfl_xor(vg, o);
            vb += __shfl_xor(vb, o); vd += __shfl_xor(vd, o);
        }

        // per-ray softmax sufficient statistics (relative to ray max)
        float mxl = sv;
        #pragma unroll
        for (int o = 32; o > 0; o >>= 1) mxl = fmaxf(mxl, __shfl_xor(mxl, o));
        float ex = expf(sv - mxl);                 // mxl wave-uniform now
        float mn = sv, S = sv, S2 = sv*sv, E = ex, SE = sv*ex, E2 = ex*ex;
        #pragma unroll
        for (int o = 32; o > 0; o >>= 1){
            mn = fminf(mn, __shfl_xor(mn, o));
            S  += __shfl_xor(S,  o);  S2 += __shfl_xor(S2, o);
            E  += __shfl_xor(E,  o);  SE += __shfl_xor(SE, o);
            E2 += __shfl_xor(E2, o);
        }
        if (lane == 0){
            const int ridx = ray0 + (tid >> 6);
            out_rgb[ridx*3+0] = vr; out_rgb[ridx*3+1] = vg; out_rgb[ridx*3+2] = vb;
            out_depth[ridx] = vd;
            stat[0*nr + ridx] = mxl; stat[1*nr + ridx] = mn;
            stat[2*nr + ridx] = S;   stat[3*nr + ridx] = S2;
            stat[4*nr + ridx] = E;   stat[5*nr + ridx] = SE;
            stat[6*nr + ridx] = E2;
        }
    }
}

// ---------------------------------------------------------------------------
// loss_k: single block, combines per-ray stats with online-softmax rescaling.
// loss = mean((s - c*e + m0)^2), c = S/E, m0 = min(sharp) computed in closed
// form (e_i in (0,1] => min is c*exp(mn-M) if c>=0 else c).
// ---------------------------------------------------------------------------
__global__ __launch_bounds__(1024) void loss_k(const float* __restrict__ st,
    int nr, int N, float* __restrict__ out_loss)
{
    const float* s_mx = st;
    const float* s_mn = st + nr;
    const float* s_S  = st + 2*nr;
    const float* s_S2 = st + 3*nr;
    const float* s_E  = st + 4*nr;
    const float* s_SE = st + 5*nr;
    const float* s_E2 = st + 6*nr;
    const int tid = threadIdx.x, lane = tid & 63, wid = tid >> 6;
    __shared__ float  shm[16];
    __shared__ double shd[6][16];

    // phase 1: global max of per-ray maxes
    float mx = -3.402823466e38f;
    for (int i = tid; i < nr; i += 1024) mx = fmaxf(mx, s_mx[i]);
    #pragma unroll
    for (int o = 32; o > 0; o >>= 1) mx = fmaxf(mx, __shfl_xor(mx, o));
    if (lane == 0) shm[wid] = mx;
    __syncthreads();
    float M = shm[0];
    #pragma unroll
    for (int i = 1; i < 16; ++i) M = fmaxf(M, shm[i]);

    // phase 2: rescaled accumulation in double
    double E=0, SE=0, E2=0, S=0, S2=0; float mn = 3.402823466e38f;
    for (int i = tid; i < nr; i += 1024){
        float mr = s_mx[i];
        double sc = exp((double)(mr - M));
        E  += sc * (double)s_E[i];
        SE += sc * (double)s_SE[i];
        E2 += sc * sc * (double)s_E2[i];
        S  += (double)s_S[i];
        S2 += (double)s_S2[i];
        mn  = fminf(mn, s_mn[i]);
    }
    #pragma unroll
    for (int o = 32; o > 0; o >>= 1){
        E  += __shfl_xor(E,  o); SE += __shfl_xor(SE, o); E2 += __shfl_xor(E2, o);
        S  += __shfl_xor(S,  o); S2 += __shfl_xor(S2, o);
        mn  = fminf(mn, __shfl_xor(mn, o));
    }
    if (lane == 0){
        shd[0][wid]=E; shd[1][wid]=SE; shd[2][wid]=E2;
        shd[3][wid]=S; shd[4][wid]=S2; shd[5][wid]=(double)mn;
    }
    __syncthreads();
    if (tid == 0){
        double E_=0,SE_=0,E2_=0,S_=0,S2_=0, mn_=1e300;
        #pragma unroll
        for (int i = 0; i < 16; ++i){
            E_ += shd[0][i]; SE_ += shd[1][i]; E2_ += shd[2][i];
            S_ += shd[3][i]; S2_ += shd[4][i];
            mn_ = fmin(mn_, shd[5][i]);
        }
        double c  = S_ / E_;
        double m0 = (c >= 0.0) ? c * exp(mn_ - (double)M) : c;  // min(sharp)
        double loss = (S2_ - 2.0*c*SE_ + 2.0*m0*S_ + c*c*E2_
                       - 2.0*c*m0*E_ + (double)N*m0*m0) / (double)N;
        out_loss[0] = (float)loss;
    }
}

extern "C" void kernel_launch(void* const* d_in, const int* in_sizes, int n_in,
                              void* d_out, int out_size, void* d_ws, size_t ws_size,
                              hipStream_t stream)
{
    const float* rays    = (const float*)d_in[0];
    const float* z_samp  = (const float*)d_in[1];
    const unsigned char* invalid = (const unsigned char*)d_in[2]; // all-false bools
    const float* W1 = (const float*)d_in[3];
    const float* b1 = (const float*)d_in[4];
    const float* W2 = (const float*)d_in[5];
    const float* b2 = (const float*)d_in[6];
    const float* W3 = (const float*)d_in[7];
    const float* b3 = (const float*)d_in[8];

    const int nrays = in_sizes[0] / 8;      // 32768
    const int N     = nrays * KSAMP;        // 2097152

    float* out       = (float*)d_out;
    float* out_rgb   = out;                             // nrays*3
    float* out_depth = out + (size_t)nrays*3;           // nrays
    float* out_w     = out + (size_t)nrays*4;           // N
    float* out_loss  = out + (size_t)nrays*4 + N;       // 1

    float* stat = (float*)d_ws;             // 7 * nrays floats (~917 KB)

    hipLaunchKernelGGL(render_k, dim3(nrays / RPB), dim3(T1), 0, stream,
        rays, z_samp, invalid, W1, b1, W2, b2, W3, b3,
        out_rgb, out_depth, out_w, stat, nrays);
    hipLaunchKernelGGL(loss_k, dim3(1), dim3(1024), 0, stream,
        stat, nrays, N, out_loss);
}

// Round 3
// 435.425 us; speedup vs baseline: 2.3568x; 2.3568x over previous
//
#include <hip/hip_runtime.h>

#define HDIM 128
#define KSAMP 64
#define RPB 2            // rays per block
#define SPB 128          // samples per block
#define T1 256           // threads in render kernel

typedef _Float16 f16x8 __attribute__((ext_vector_type(8)));
typedef float    f32x16 __attribute__((ext_vector_type(16)));

__device__ __forceinline__ float sigmoidf_(float x){ return 1.f/(1.f+expf(-x)); }

// ---------------------------------------------------------------------------
// pack_k: split W2 (128x128 f32) into f16 hi/lo B-fragments, laid out in the
// exact linear order render_k's waves read them:
//   dword idx = ((((p*4+kk)*4+nt)*2+h)*64+lane)*4+d      (h: 0=hi, 1=lo)
//   k = p*64 + kk*16 + (lane>>5)*8 + 2d(+1),  n = nt*32 + (lane&31)
// The (lane-half, elem)->k convention here matches the A-side construction in
// render_k, so the HW's internal k permutation cancels.
// ---------------------------------------------------------------------------
__global__ __launch_bounds__(256) void pack_k(const float* __restrict__ W2,
                                              unsigned int* __restrict__ wsB)
{
    int sIdx = blockIdx.x*256 + threadIdx.x;   // 8192 slots (hi+lo written per slot)
    int d    = sIdx & 3;
    int lane = (sIdx >> 2) & 63;
    int nt   = (sIdx >> 8) & 3;
    int kk   = (sIdx >> 10) & 3;
    int p    = (sIdx >> 12) & 1;
    int k0 = p*64 + kk*16 + ((lane>>5)<<3) + 2*d;
    int n  = nt*32 + (lane & 31);
    float x0 = W2[k0*HDIM + n];
    float x1 = W2[(k0+1)*HDIM + n];
    _Float16 h0 = (_Float16)x0; _Float16 l0 = (_Float16)(x0 - (float)h0);
    _Float16 h1 = (_Float16)x1; _Float16 l1 = (_Float16)(x1 - (float)h1);
    union { _Float16 h[2]; unsigned int u; } uh, ul;
    uh.h[0] = h0; uh.h[1] = h1;
    ul.h[0] = l0; ul.h[1] = l1;
    int base = ((((p*4 + kk)*4 + nt)*2 + 0)*64 + lane)*4 + d;
    wsB[base]       = uh.u;
    wsB[base + 256] = ul.u;          // h=1 is +64*4 dwords
}

// ---------------------------------------------------------------------------
// render_k: block = 2 rays (M=128 samples), 4 waves. Wave w owns samples
// [32w,32w+32). Layer-2 = 3-pass f16-split MFMA (32x32x16), K phased 2x64
// with B-fragments staged in LDS. h1 A-fragments built in registers from the
// ow/dw factorization. Epilogue: h2 -> swizzled LDS -> layer 3 -> compositing
// + per-ray softmax sufficient statistics.
// ---------------------------------------------------------------------------
__global__ __launch_bounds__(T1) void render_k(
    const float* __restrict__ rays, const float* __restrict__ z_samp,
    const unsigned char* __restrict__ invalid,
    const float* __restrict__ W1, const float* __restrict__ b1,
    const unsigned int* __restrict__ wsB, const float* __restrict__ b2,
    const float* __restrict__ W3, const float* __restrict__ b3,
    float* __restrict__ out_rgb, float* __restrict__ out_depth,
    float* __restrict__ out_w, float* __restrict__ stat, int nr)
{
    __shared__ float lds[16384];     // 64 KiB static
    // regions: B-frag buffer dwords [0,8192); ow [8192,8448); dw [8448,8704);
    // epilogue reuses all 16384 as h2t.

    const int tid  = threadIdx.x;
    const int lane = tid & 63;
    const int w    = tid >> 6;                 // wave 0..3
    const int ray0 = blockIdx.x * RPB;
    const int sOfs = 32*w + (lane & 31);       // this lane's A-row sample
    const float z  = z_samp[(size_t)ray0*KSAMP + sOfs];

    // ---- ow/dw factorization of layer 1 (per ray, per feature) ----
    {
        int f = tid & 127, r = tid >> 7;
        const float* rp = rays + (size_t)(ray0 + r) * 8;
        float w0 = W1[f], w1 = W1[HDIM+f], w2 = W1[2*HDIM+f];
        lds[8192 + r*HDIM + f] = fmaf(rp[0],w0, fmaf(rp[1],w1, fmaf(rp[2],w2, b1[f])));
        lds[8448 + r*HDIM + f] = fmaf(rp[3],w0, fmaf(rp[4],w1, rp[5]*w2));
    }

    // ---- acc init with b2 (C/D: col = lane&31) ----
    f32x16 acc[4];
    #pragma unroll
    for (int nt = 0; nt < 4; ++nt){
        float bv = b2[nt*32 + (lane & 31)];
        #pragma unroll
        for (int r = 0; r < 16; ++r) acc[nt][r] = bv;
    }

    const float* owp = lds + 8192 + (w>>1)*HDIM;   // wave's ray
    const float* dwp = lds + 8448 + (w>>1)*HDIM;

    for (int p = 0; p < 2; ++p){
        __syncthreads();   // ow/dw visible (p=0); B-buf reads done (p=1)
        // ---- stage this phase's B fragments: 8192 dwords, linear ----
        {
            const float4* src = (const float4*)(wsB + p*8192);
            #pragma unroll
            for (int i = 0; i < 8; ++i)
                *(float4*)&lds[(i*T1 + tid)*4] = src[i*T1 + tid];
        }
        __syncthreads();
        #pragma unroll
        for (int kk = 0; kk < 4; ++kk){
            // ---- A fragment: h1 hi/lo for f = fb..fb+7, sample sOfs ----
            int fb = p*64 + kk*16 + ((lane>>5)<<3);
            float4 owa = *(const float4*)&owp[fb];
            float4 owb = *(const float4*)&owp[fb+4];
            float4 dwa = *(const float4*)&dwp[fb];
            float4 dwb = *(const float4*)&dwp[fb+4];
            float hv[8] = { fmaf(z,dwa.x,owa.x), fmaf(z,dwa.y,owa.y),
                            fmaf(z,dwa.z,owa.z), fmaf(z,dwa.w,owa.w),
                            fmaf(z,dwb.x,owb.x), fmaf(z,dwb.y,owb.y),
                            fmaf(z,dwb.z,owb.z), fmaf(z,dwb.w,owb.w) };
            f16x8 ah, al;
            #pragma unroll
            for (int j = 0; j < 8; ++j){
                float x = fmaxf(hv[j], 0.f);
                _Float16 hi = (_Float16)x;
                ah[j] = hi;
                al[j] = (_Float16)(x - (float)hi);
            }
            // ---- 4 N-tiles x 3 MFMA passes ----
            #pragma unroll
            for (int nt = 0; nt < 4; ++nt){
                int bbase = (((kk*4 + nt)*2)*64 + lane)*4;
                f16x8 bh = *(const f16x8*)&lds[bbase];
                f16x8 bl = *(const f16x8*)&lds[bbase + 256];
                acc[nt] = __builtin_amdgcn_mfma_f32_32x32x16_f16(ah, bh, acc[nt], 0,0,0);
                acc[nt] = __builtin_amdgcn_mfma_f32_32x32x16_f16(ah, bl, acc[nt], 0,0,0);
                acc[nt] = __builtin_amdgcn_mfma_f32_32x32x16_f16(al, bh, acc[nt], 0,0,0);
            }
        }
    }
    __syncthreads();   // all MFMA LDS reads done before h2t overwrite

    // ---- h2 = relu(acc) -> LDS h2t[f][s ^ (f&31)] (conflict-free both ways) --
    #pragma unroll
    for (int nt = 0; nt < 4; ++nt){
        int f = nt*32 + (lane & 31);
        #pragma unroll
        for (int r = 0; r < 16; ++r){
            int s = 32*w + (r & 3) + 8*(r >> 2) + 4*(lane >> 5);
            lds[f*SPB + (s ^ (f & 31))] = fmaxf(acc[nt][r], 0.f);
        }
    }
    __syncthreads();

    // ---- layer 3 + compositing: threads 0..127, wave handles one ray ----
    if (tid < SPB){
        const int lane2 = tid & 63;
        float4 b3v = *(const float4*)&b3[0];
        float p0 = b3v.x, p1 = b3v.y, p2 = b3v.z, p3 = b3v.w;
        #pragma unroll 8
        for (int k = 0; k < HDIM; ++k){
            float h = lds[k*SPB + (tid ^ (k & 31))];
            float4 w3 = *(const float4*)&W3[k*4];   // wave-uniform
            p0 = fmaf(h,w3.x,p0); p1 = fmaf(h,w3.y,p1);
            p2 = fmaf(h,w3.z,p2); p3 = fmaf(h,w3.w,p3);
        }
        const size_t gidx = (size_t)ray0 * KSAMP + tid;
        const float sigma = p3;
        const float sv = invalid[gidx] ? 0.f : sigma;
        const float ze = z_samp[gidx];

        float zn = __shfl_down(ze, 1);
        float delta = (lane2 == 63) ? 1e10f : (zn - ze);
        float alpha = 1.f - expf(-fabsf(delta) * fmaxf(sigma, 0.f));
        float shifted = 1.f - alpha + 1e-10f;
        float pr = shifted;
        #pragma unroll
        for (int o = 1; o < 64; o <<= 1){
            float v = __shfl_up(pr, o);
            if (lane2 >= o) pr *= v;
        }
        float T = __shfl_up(pr, 1);
        if (lane2 == 0) T = 1.f;
        const float wgt = alpha * T;
        out_w[gidx] = wgt;

        float rr = sigmoidf_(p0), gg = sigmoidf_(p1), bb = sigmoidf_(p2);
        float vr = wgt*rr, vg = wgt*gg, vb = wgt*bb, vd = wgt*ze;
        #pragma unroll
        for (int o = 32; o > 0; o >>= 1){
            vr += __shfl_xor(vr, o); vg += __shfl_xor(vg, o);
            vb += __shfl_xor(vb, o); vd += __shfl_xor(vd, o);
        }

        float mxl = sv;
        #pragma unroll
        for (int o = 32; o > 0; o >>= 1) mxl = fmaxf(mxl, __shfl_xor(mxl, o));
        float ex = expf(sv - mxl);
        float mn = sv, S = sv, S2 = sv*sv, E = ex, SE = sv*ex, E2 = ex*ex;
        #pragma unroll
        for (int o = 32; o > 0; o >>= 1){
            mn = fminf(mn, __shfl_xor(mn, o));
            S  += __shfl_xor(S,  o);  S2 += __shfl_xor(S2, o);
            E  += __shfl_xor(E,  o);  SE += __shfl_xor(SE, o);
            E2 += __shfl_xor(E2, o);
        }
        if (lane2 == 0){
            const int ridx = ray0 + (tid >> 6);
            out_rgb[ridx*3+0] = vr; out_rgb[ridx*3+1] = vg; out_rgb[ridx*3+2] = vb;
            out_depth[ridx] = vd;
            stat[0*nr + ridx] = mxl; stat[1*nr + ridx] = mn;
            stat[2*nr + ridx] = S;   stat[3*nr + ridx] = S2;
            stat[4*nr + ridx] = E;   stat[5*nr + ridx] = SE;
            stat[6*nr + ridx] = E2;
        }
    }
}

// ---------------------------------------------------------------------------
// loss_k: combine per-ray stats with online-softmax rescaling (unchanged).
// ---------------------------------------------------------------------------
__global__ __launch_bounds__(1024) void loss_k(const float* __restrict__ st,
    int nr, int N, float* __restrict__ out_loss)
{
    const float* s_mx = st;
    const float* s_mn = st + nr;
    const float* s_S  = st + 2*nr;
    const float* s_S2 = st + 3*nr;
    const float* s_E  = st + 4*nr;
    const float* s_SE = st + 5*nr;
    const float* s_E2 = st + 6*nr;
    const int tid = threadIdx.x, lane = tid & 63, wid = tid >> 6;
    __shared__ float  shm[16];
    __shared__ double shd[6][16];

    float mx = -3.402823466e38f;
    for (int i = tid; i < nr; i += 1024) mx = fmaxf(mx, s_mx[i]);
    #pragma unroll
    for (int o = 32; o > 0; o >>= 1) mx = fmaxf(mx, __shfl_xor(mx, o));
    if (lane == 0) shm[wid] = mx;
    __syncthreads();
    float M = shm[0];
    #pragma unroll
    for (int i = 1; i < 16; ++i) M = fmaxf(M, shm[i]);

    double E=0, SE=0, E2=0, S=0, S2=0; float mn = 3.402823466e38f;
    for (int i = tid; i < nr; i += 1024){
        float mr = s_mx[i];
        double sc = exp((double)(mr - M));
        E  += sc * (double)s_E[i];
        SE += sc * (double)s_SE[i];
        E2 += sc * sc * (double)s_E2[i];
        S  += (double)s_S[i];
        S2 += (double)s_S2[i];
        mn  = fminf(mn, s_mn[i]);
    }
    #pragma unroll
    for (int o = 32; o > 0; o >>= 1){
        E  += __shfl_xor(E,  o); SE += __shfl_xor(SE, o); E2 += __shfl_xor(E2, o);
        S  += __shfl_xor(S,  o); S2 += __shfl_xor(S2, o);
        mn  = fminf(mn, __shfl_xor(mn, o));
    }
    if (lane == 0){
        shd[0][wid]=E; shd[1][wid]=SE; shd[2][wid]=E2;
        shd[3][wid]=S; shd[4][wid]=S2; shd[5][wid]=(double)mn;
    }
    __syncthreads();
    if (tid == 0){
        double E_=0,SE_=0,E2_=0,S_=0,S2_=0, mn_=1e300;
        #pragma unroll
        for (int i = 0; i < 16; ++i){
            E_ += shd[0][i]; SE_ += shd[1][i]; E2_ += shd[2][i];
            S_ += shd[3][i]; S2_ += shd[4][i];
            mn_ = fmin(mn_, shd[5][i]);
        }
        double c  = S_ / E_;
        double m0 = (c >= 0.0) ? c * exp(mn_ - (double)M) : c;
        double loss = (S2_ - 2.0*c*SE_ + 2.0*m0*S_ + c*c*E2_
                       - 2.0*c*m0*E_ + (double)N*m0*m0) / (double)N;
        out_loss[0] = (float)loss;
    }
}

extern "C" void kernel_launch(void* const* d_in, const int* in_sizes, int n_in,
                              void* d_out, int out_size, void* d_ws, size_t ws_size,
                              hipStream_t stream)
{
    const float* rays    = (const float*)d_in[0];
    const float* z_samp  = (const float*)d_in[1];
    const unsigned char* invalid = (const unsigned char*)d_in[2];
    const float* W1 = (const float*)d_in[3];
    const float* b1 = (const float*)d_in[4];
    const float* W2 = (const float*)d_in[5];
    const float* b2 = (const float*)d_in[6];
    const float* W3 = (const float*)d_in[7];
    const float* b3 = (const float*)d_in[8];

    const int nrays = in_sizes[0] / 8;      // 32768
    const int N     = nrays * KSAMP;        // 2097152

    float* out       = (float*)d_out;
    float* out_rgb   = out;
    float* out_depth = out + (size_t)nrays*3;
    float* out_w     = out + (size_t)nrays*4;
    float* out_loss  = out + (size_t)nrays*4 + N;

    unsigned int* wsB = (unsigned int*)d_ws;          // 16384 dwords (64 KB)
    float* stat = (float*)d_ws + 16384;               // 7*nrays floats

    hipLaunchKernelGGL(pack_k, dim3(32), dim3(256), 0, stream, W2, wsB);
    hipLaunchKernelGGL(render_k, dim3(nrays / RPB), dim3(T1), 0, stream,
        rays, z_samp, invalid, W1, b1, wsB, b2, W3, b3,
        out_rgb, out_depth, out_w, stat, nrays);
    hipLaunchKernelGGL(loss_k, dim3(1), dim3(1024), 0, stream,
        stat, nrays, N, out_loss);
}